// Round 1
// baseline (212.329 us; speedup 1.0000x reference)
//
#include <hip/hip_runtime.h>
#include <math.h>

#define B_    16
#define T_    50
#define C_    80
#define NTOT  363888          // total cells across scales: 17328 + 69312 + 277248
#define OFF0  0
#define OFF1  17328
#define OFF2  86640
#define NCONFBLK 120

// per-scale grid widths and anchor sizes in grid units (anchor_px / stride, stride = 608/W, exact)
__device__ __constant__ int   cW[3]     = {19, 38, 76};
__device__ __constant__ int   cOFF[3]   = {OFF0, OFF1, OFF2};
__device__ __constant__ float cAW[3][3] = {{3.625f, 4.875f, 11.65625f},
                                           {1.875f, 3.875f, 3.6875f},
                                           {1.25f,  2.0f,   4.125f}};
__device__ __constant__ float cAH[3][3] = {{2.8125f, 6.1875f, 10.1875f},
                                           {3.8125f, 2.8125f, 7.4375f},
                                           {1.625f,  3.75f,   2.875f}};

// min(softplus(x), 100) == min(-clip(log(sigmoid(-x))... ), matches -clip(log p,-100) terms
__device__ __forceinline__ float SPc(float x) {
    float sp = (x > 0.f) ? (x + log1pf(expf(-x))) : log1pf(expf(x));
    return fminf(sp, 100.f);
}

__global__ void init_k(int* __restrict__ winner, int* __restrict__ lcell,
                       double* __restrict__ sums, unsigned char* __restrict__ noobj) {
    int i = blockIdx.x * blockDim.x + threadIdx.x;
    if (i < NTOT) { winner[i] = -1; noobj[i] = 1; }
    if (i < 3 * B_ * T_) lcell[i] = -1;
    if (i < 24 + NCONFBLK * 3) sums[i] = 0.0;
}

// one block per batch item; thread t handles label t
__global__ void assign_k(const float* __restrict__ labels, int* __restrict__ winner,
                         unsigned char* __restrict__ noobj, int* __restrict__ lcell) {
    int b = blockIdx.x;
    int t = threadIdx.x;
    __shared__ int flags[T_];
    __shared__ int nlabel;
    if (t < T_) {
        const float* L = labels + (b * T_ + t) * 5;
        float s = L[0] + L[1] + L[2] + L[3] + L[4];
        flags[t] = (s > 0.f) ? 1 : 0;
    }
    __syncthreads();
    if (t == 0) {
        int n = 0;
        for (int i = 0; i < T_; i++) n += flags[i];
        nlabel = n;
    }
    __syncthreads();
    if (t >= T_ || t >= nlabel) return;

    const float* L = labels + (b * T_ + t) * 5;
    float lx = L[1] / 608.f, ly = L[2] / 608.f, lw = L[3] / 608.f, lh = L[4] / 608.f;

    for (int s = 0; s < 3; s++) {
        int W = cW[s];
        float gx = lx * W, gy = ly * W, gw = lw * W, gh = lh * W;
        int gi = (int)floorf(gx), gj = (int)floorf(gy);
        float ious[3];
        float best_iou = -1.f;
        int best = 0;
        #pragma unroll
        for (int a = 0; a < 3; a++) {
            float aw = cAW[s][a], ah = cAH[s][a];
            float inter = (fminf(gw, aw) + 1.f) * (fminf(gh, ah) + 1.f);
            float iou = inter / ((gw + 1.f) * (gh + 1.f) + (aw + 1.f) * (ah + 1.f) - inter + 1e-16f);
            ious[a] = iou;
            if (iou > best_iou) { best_iou = iou; best = a; }
        }
        bool inb = (gi >= 0) && (gi < W) && (gj >= 0) && (gj < W);
        if (!inb) continue;   // scatter mode='drop'
        #pragma unroll
        for (int a = 0; a < 3; a++)
            if (ious[a] > 0.5f)
                noobj[cOFF[s] + ((b * 3 + a) * W + gj) * W + gi] = 0;
        int cell = cOFF[s] + ((b * 3 + best) * W + gj) * W + gi;
        atomicMax(&winner[cell], t);     // consistent "last write wins" for duplicate cells
        lcell[(s * B_ + b) * T_ + t] = cell;
    }
}

// one block per scale; thread id -> (b,t); only winning labels contribute
__global__ __launch_bounds__(1024) void pos_k(
    const float* __restrict__ p0, const float* __restrict__ p1, const float* __restrict__ p2,
    const float* __restrict__ labels, const int* __restrict__ winner,
    const int* __restrict__ lcell, double* __restrict__ sums) {
    int s = blockIdx.x;
    int id = threadIdx.x;
    double v0 = 0, v1 = 0, v2 = 0, v3 = 0, v4 = 0, v5 = 0, v6 = 0;
    if (id < B_ * T_) {
        int b = id / T_, t = id % T_;
        int cell = lcell[(s * B_ + b) * T_ + t];
        if (cell >= 0 && winner[cell] == t) {
            int W = cW[s], HW = W * W;
            int local = cell - cOFF[s];
            int gi = local % W;
            int gj = (local / W) % W;
            int a  = (local / HW) % 3;
            const float* L = labels + (b * T_ + t) * 5;
            int cls = (int)L[0];
            float gx = (L[1] / 608.f) * W, gy = (L[2] / 608.f) * W;
            float gw = (L[3] / 608.f) * W, gh = (L[4] / 608.f) * W;
            float tx = gx - gi, ty = gy - gj;
            float tw = logf(gw / cAW[s][a] + 1e-16f);
            float th = logf(gh / cAH[s][a] + 1e-16f);
            const float* p = (s == 0) ? p0 : ((s == 1) ? p1 : p2);
            int base = (b * 255 + a * 85) * HW + gj * W + gi;
            float x0 = p[base];
            float x1 = p[base + HW];
            float x2 = p[base + 2 * HW];
            float x3 = p[base + 3 * HW];
            float x4 = p[base + 4 * HW];
            v0 = (double)(tx * SPc(-x0) + (1.f - tx) * SPc(x0));
            v1 = (double)(ty * SPc(-x1) + (1.f - ty) * SPc(x1));
            float dw = x2 - tw, dh = x3 - th;
            v2 = (double)(dw * dw);
            v3 = (double)(dh * dh);
            v4 = (double)SPc(-x4);
            double cs = 0.0;
            for (int c = 0; c < C_; c++) {
                float xc = p[base + (5 + c) * HW];
                cs += (double)((c == cls) ? SPc(-xc) : SPc(xc));
            }
            v5 = cs;
            v6 = 1.0;
        }
    }
    // block reduction: wave shuffle then LDS
    int lane = id & 63, wid = id >> 6;
    #pragma unroll
    for (int off = 32; off; off >>= 1) {
        v0 += __shfl_down(v0, off);
        v1 += __shfl_down(v1, off);
        v2 += __shfl_down(v2, off);
        v3 += __shfl_down(v3, off);
        v4 += __shfl_down(v4, off);
        v5 += __shfl_down(v5, off);
        v6 += __shfl_down(v6, off);
    }
    __shared__ double sh[16][7];
    if (lane == 0) {
        sh[wid][0] = v0; sh[wid][1] = v1; sh[wid][2] = v2; sh[wid][3] = v3;
        sh[wid][4] = v4; sh[wid][5] = v5; sh[wid][6] = v6;
    }
    __syncthreads();
    if (id == 0) {
        double tot[7] = {0, 0, 0, 0, 0, 0, 0};
        for (int w = 0; w < 16; w++)
            for (int k = 0; k < 7; k++) tot[k] += sh[w][k];
        for (int k = 0; k < 7; k++) sums[s * 8 + k] = tot[k];
    }
}

// grid-stride over all cells: softplus(conf logit) where noobj
__global__ void conf_k(const float* __restrict__ p0, const float* __restrict__ p1,
                       const float* __restrict__ p2, const unsigned char* __restrict__ noobj,
                       double* __restrict__ part) {
    double a0 = 0, a1 = 0, a2 = 0;
    for (int idx = blockIdx.x * blockDim.x + threadIdx.x; idx < NTOT;
         idx += gridDim.x * blockDim.x) {
        int s, off;
        const float* p;
        if (idx < OFF1)      { s = 0; off = OFF0; p = p0; }
        else if (idx < OFF2) { s = 1; off = OFF1; p = p1; }
        else                 { s = 2; off = OFF2; p = p2; }
        if (!noobj[idx]) continue;
        int W = cW[s], HW = W * W;
        int local = idx - off;
        int ba = local / HW, pos = local % HW;
        int b = ba / 3, a = ba % 3;
        float x = p[(b * 255 + a * 85 + 4) * HW + pos];
        float v = SPc(x);
        if (s == 0) a0 += v; else if (s == 1) a1 += v; else a2 += v;
    }
    int lane = threadIdx.x & 63, wid = threadIdx.x >> 6;
    #pragma unroll
    for (int off = 32; off; off >>= 1) {
        a0 += __shfl_down(a0, off);
        a1 += __shfl_down(a1, off);
        a2 += __shfl_down(a2, off);
    }
    __shared__ double sh[4][3];
    if (lane == 0) { sh[wid][0] = a0; sh[wid][1] = a1; sh[wid][2] = a2; }
    __syncthreads();
    if (threadIdx.x == 0) {
        double t0 = 0, t1 = 0, t2 = 0;
        for (int w = 0; w < 4; w++) { t0 += sh[w][0]; t1 += sh[w][1]; t2 += sh[w][2]; }
        part[blockIdx.x * 3 + 0] = t0;
        part[blockIdx.x * 3 + 1] = t1;
        part[blockIdx.x * 3 + 2] = t2;
    }
}

__global__ void final_k(const double* __restrict__ sums, const double* __restrict__ part,
                        float* __restrict__ out) {
    if (threadIdx.x != 0 || blockIdx.x != 0) return;
    double conf2[3] = {0, 0, 0};
    for (int blk = 0; blk < NCONFBLK; blk++) {
        conf2[0] += part[blk * 3 + 0];
        conf2[1] += part[blk * 3 + 1];
        conf2[2] += part[blk * 3 + 2];
    }
    const double Ns[3] = {17328.0, 69312.0, 277248.0};
    double loss = 0.0;
    for (int s = 0; s < 3; s++) {
        double N = Ns[s];
        double lx = sums[s * 8 + 0] / N;
        double ly = sums[s * 8 + 1] / N;
        double lw = sums[s * 8 + 2] / N;
        double lh = sums[s * 8 + 3] / N;
        double c1 = sums[s * 8 + 4] / N;
        double np = sums[s * 8 + 6];
        double lcls = (np > 0.0) ? (sums[s * 8 + 5] / (np * 80.0)) : 0.0;
        double c2 = 0.5 * conf2[s] / N;
        loss += 2.5 * (lx + ly) + 2.5 * (lw + lh) + (c1 + c2) + lcls;
    }
    out[0] = (float)loss;
}

extern "C" void kernel_launch(void* const* d_in, const int* in_sizes, int n_in,
                              void* d_out, int out_size, void* d_ws, size_t ws_size,
                              hipStream_t stream) {
    const float* p0     = (const float*)d_in[0];
    const float* p1     = (const float*)d_in[1];
    const float* p2     = (const float*)d_in[2];
    const float* labels = (const float*)d_in[3];
    float* out = (float*)d_out;

    char* ws = (char*)d_ws;
    int* winner         = (int*)ws;                                   // NTOT ints
    int* lcell          = (int*)(ws + (size_t)NTOT * 4);              // 3*B*T ints (9600 B)
    double* sums        = (double*)(ws + (size_t)NTOT * 4 + 9600);    // 24 doubles (8-aligned)
    double* part        = sums + 24;                                  // NCONFBLK*3 doubles
    unsigned char* noobj = (unsigned char*)(part + NCONFBLK * 3);     // NTOT bytes

    init_k<<<(NTOT + 255) / 256, 256, 0, stream>>>(winner, lcell, sums, noobj);
    assign_k<<<B_, 64, 0, stream>>>(labels, winner, noobj, lcell);
    pos_k<<<3, 1024, 0, stream>>>(p0, p1, p2, labels, winner, lcell, sums);
    conf_k<<<NCONFBLK, 256, 0, stream>>>(p0, p1, p2, noobj, part);
    final_k<<<1, 1, 0, stream>>>(sums, part, out);
}

// Round 2
// 67.682 us; speedup vs baseline: 3.1371x; 3.1371x over previous
//
#include <hip/hip_runtime.h>
#include <math.h>

#define B_    16
#define T_    50
#define C_    80
#define NTOT  363888          // total cells across scales: 17328 + 69312 + 277248
#define OFF0  0
#define OFF1  17328
#define OFF2  86640
#define NCONFBLK 120
#define NCAND (3 * B_ * T_)   // 2400 candidates (scale, b, t)

// per-scale grid widths and anchor sizes in grid units (anchor_px / stride, stride = 608/W, exact)
__device__ __constant__ int   cW[3]     = {19, 38, 76};
__device__ __constant__ int   cOFF[3]   = {OFF0, OFF1, OFF2};
__device__ __constant__ float cAW[3][3] = {{3.625f, 4.875f, 11.65625f},
                                           {1.875f, 3.875f, 3.6875f},
                                           {1.25f,  2.0f,   4.125f}};
__device__ __constant__ float cAH[3][3] = {{2.8125f, 6.1875f, 10.1875f},
                                           {3.8125f, 2.8125f, 7.4375f},
                                           {1.625f,  3.75f,   2.875f}};

// min(softplus(x), 100) == the -clip(log p, -100) BCE terms exactly
__device__ __forceinline__ float SPc(float x) {
    float sp = (x > 0.f) ? (x + log1pf(expf(-x))) : log1pf(expf(x));
    return fminf(sp, 100.f);
}

__global__ void init_k(int* __restrict__ winner, int* __restrict__ lcell,
                       unsigned char* __restrict__ noobj) {
    int i = blockIdx.x * blockDim.x + threadIdx.x;
    if (i < NTOT) { winner[i] = -1; noobj[i] = 1; }
    if (i < NCAND) lcell[i] = -1;
}

// one block per batch item; thread t handles label t
__global__ void assign_k(const float* __restrict__ labels, int* __restrict__ winner,
                         unsigned char* __restrict__ noobj, int* __restrict__ lcell) {
    int b = blockIdx.x;
    int t = threadIdx.x;
    __shared__ int flags[T_];
    __shared__ int nlabel;
    if (t < T_) {
        const float* L = labels + (b * T_ + t) * 5;
        float s = L[0] + L[1] + L[2] + L[3] + L[4];
        flags[t] = (s > 0.f) ? 1 : 0;
    }
    __syncthreads();
    if (t == 0) {
        int n = 0;
        for (int i = 0; i < T_; i++) n += flags[i];
        nlabel = n;
    }
    __syncthreads();
    if (t >= T_ || t >= nlabel) return;

    const float* L = labels + (b * T_ + t) * 5;
    float lx = L[1] / 608.f, ly = L[2] / 608.f, lw = L[3] / 608.f, lh = L[4] / 608.f;

    for (int s = 0; s < 3; s++) {
        int W = cW[s];
        float gx = lx * W, gy = ly * W, gw = lw * W, gh = lh * W;
        int gi = (int)floorf(gx), gj = (int)floorf(gy);
        float ious[3];
        float best_iou = -1.f;
        int best = 0;
        #pragma unroll
        for (int a = 0; a < 3; a++) {
            float aw = cAW[s][a], ah = cAH[s][a];
            float inter = (fminf(gw, aw) + 1.f) * (fminf(gh, ah) + 1.f);
            float iou = inter / ((gw + 1.f) * (gh + 1.f) + (aw + 1.f) * (ah + 1.f) - inter + 1e-16f);
            ious[a] = iou;
            if (iou > best_iou) { best_iou = iou; best = a; }
        }
        bool inb = (gi >= 0) && (gi < W) && (gj >= 0) && (gj < W);
        if (!inb) continue;   // scatter mode='drop'
        #pragma unroll
        for (int a = 0; a < 3; a++)
            if (ious[a] > 0.5f)
                noobj[cOFF[s] + ((b * 3 + a) * W + gj) * W + gi] = 0;
        int cell = cOFF[s] + ((b * 3 + best) * W + gj) * W + gi;
        atomicMax(&winner[cell], t);     // consistent "last write wins" for duplicate cells
        lcell[(s * B_ + b) * T_ + t] = cell;   // == lcell[s*800 + b*50 + t]
    }
}

// one WAVE per candidate (s,b,t): lanes parallelize the 80-class BCE loads.
// 2400 waves -> 600 blocks x 256. Each wave writes 7 partials to a unique slot.
__global__ __launch_bounds__(256) void pos_k(
    const float* __restrict__ p0, const float* __restrict__ p1, const float* __restrict__ p2,
    const float* __restrict__ labels, const int* __restrict__ winner,
    const int* __restrict__ lcell, double* __restrict__ part2) {
    int wg = blockIdx.x * 4 + (threadIdx.x >> 6);   // global wave id = candidate id
    int lane = threadIdx.x & 63;
    int s = wg / (B_ * T_);
    int bt = wg - s * (B_ * T_);
    int b = bt / T_, t = bt - b * T_;

    int cell = lcell[wg];
    bool win = (cell >= 0) && (winner[cell] == t);   // wave-uniform

    double clsum = 0.0;
    int W = cW[s], HW = W * W;
    int base = 0, a = 0;
    const float* p = (s == 0) ? p0 : ((s == 1) ? p1 : p2);
    if (win) {
        int local = cell - cOFF[s];
        int gi = local % W;
        int gj = (local / W) % W;
        a = (local / HW) % 3;
        const float* L = labels + (b * T_ + t) * 5;
        int cls = (int)L[0];
        base = (b * 255 + a * 85) * HW + gj * W + gi;
        for (int c = lane; c < C_; c += 64) {
            float xc = p[base + (5 + c) * HW];
            clsum += (double)((c == cls) ? SPc(-xc) : SPc(xc));
        }
    }
    #pragma unroll
    for (int off = 32; off; off >>= 1) clsum += __shfl_down(clsum, off);

    if (lane == 0) {
        double o0 = 0, o1 = 0, o2 = 0, o3 = 0, o4 = 0, o5 = 0, o6 = 0;
        if (win) {
            int local = cell - cOFF[s];
            int gi = local % W;
            int gj = (local / W) % W;
            const float* L = labels + (b * T_ + t) * 5;
            float gx = (L[1] / 608.f) * W, gy = (L[2] / 608.f) * W;
            float gw = (L[3] / 608.f) * W, gh = (L[4] / 608.f) * W;
            float tx = gx - gi, ty = gy - gj;
            float tw = logf(gw / cAW[s][a] + 1e-16f);
            float th = logf(gh / cAH[s][a] + 1e-16f);
            float x0 = p[base];
            float x1 = p[base + HW];
            float x2 = p[base + 2 * HW];
            float x3 = p[base + 3 * HW];
            float x4 = p[base + 4 * HW];
            o0 = (double)(tx * SPc(-x0) + (1.f - tx) * SPc(x0));
            o1 = (double)(ty * SPc(-x1) + (1.f - ty) * SPc(x1));
            float dw = x2 - tw, dh = x3 - th;
            o2 = (double)(dw * dw);
            o3 = (double)(dh * dh);
            o4 = (double)SPc(-x4);
            o5 = clsum;
            o6 = 1.0;
        }
        double* dst = part2 + (size_t)wg * 8;
        dst[0] = o0; dst[1] = o1; dst[2] = o2; dst[3] = o3;
        dst[4] = o4; dst[5] = o5; dst[6] = o6;
    }
}

// grid-stride over all cells: softplus(conf logit) where noobj
__global__ void conf_k(const float* __restrict__ p0, const float* __restrict__ p1,
                       const float* __restrict__ p2, const unsigned char* __restrict__ noobj,
                       double* __restrict__ part) {
    double a0 = 0, a1 = 0, a2 = 0;
    for (int idx = blockIdx.x * blockDim.x + threadIdx.x; idx < NTOT;
         idx += gridDim.x * blockDim.x) {
        int s, off;
        const float* p;
        if (idx < OFF1)      { s = 0; off = OFF0; p = p0; }
        else if (idx < OFF2) { s = 1; off = OFF1; p = p1; }
        else                 { s = 2; off = OFF2; p = p2; }
        if (!noobj[idx]) continue;
        int W = cW[s], HW = W * W;
        int local = idx - off;
        int ba = local / HW, pos = local % HW;
        int b = ba / 3, a = ba % 3;
        float x = p[(b * 255 + a * 85 + 4) * HW + pos];
        float v = SPc(x);
        if (s == 0) a0 += v; else if (s == 1) a1 += v; else a2 += v;
    }
    int lane = threadIdx.x & 63, wid = threadIdx.x >> 6;
    #pragma unroll
    for (int off = 32; off; off >>= 1) {
        a0 += __shfl_down(a0, off);
        a1 += __shfl_down(a1, off);
        a2 += __shfl_down(a2, off);
    }
    __shared__ double sh[4][3];
    if (lane == 0) { sh[wid][0] = a0; sh[wid][1] = a1; sh[wid][2] = a2; }
    __syncthreads();
    if (threadIdx.x == 0) {
        double t0 = 0, t1 = 0, t2 = 0;
        for (int w = 0; w < 4; w++) { t0 += sh[w][0]; t1 += sh[w][1]; t2 += sh[w][2]; }
        part[blockIdx.x * 3 + 0] = t0;
        part[blockIdx.x * 3 + 1] = t1;
        part[blockIdx.x * 3 + 2] = t2;
    }
}

// deterministic tree-reduce of the 2400x7 pos partials + 120x3 conf partials
__global__ __launch_bounds__(256) void final_k(const double* __restrict__ part2,
                                               const double* __restrict__ part,
                                               float* __restrict__ out) {
    int tid = threadIdx.x;
    double acc[3][7];
    #pragma unroll
    for (int s = 0; s < 3; s++)
        #pragma unroll
        for (int k = 0; k < 7; k++) acc[s][k] = 0.0;
    for (int i = tid; i < NCAND; i += 256) {
        int s = i / (B_ * T_);
        const double* src = part2 + (size_t)i * 8;
        #pragma unroll
        for (int k = 0; k < 7; k++) acc[s][k] += src[k];
    }
    double cacc[3] = {0, 0, 0};
    for (int i = tid; i < NCONFBLK; i += 256) {
        cacc[0] += part[i * 3 + 0];
        cacc[1] += part[i * 3 + 1];
        cacc[2] += part[i * 3 + 2];
    }
    int lane = tid & 63, wid = tid >> 6;
    #pragma unroll
    for (int off = 32; off; off >>= 1) {
        #pragma unroll
        for (int s = 0; s < 3; s++)
            #pragma unroll
            for (int k = 0; k < 7; k++) acc[s][k] += __shfl_down(acc[s][k], off);
        #pragma unroll
        for (int s = 0; s < 3; s++) cacc[s] += __shfl_down(cacc[s], off);
    }
    __shared__ double sh[4][24];
    if (lane == 0) {
        #pragma unroll
        for (int s = 0; s < 3; s++) {
            #pragma unroll
            for (int k = 0; k < 7; k++) sh[wid][s * 7 + k] = acc[s][k];
            sh[wid][21 + s] = cacc[s];
        }
    }
    __syncthreads();
    if (tid == 0) {
        double tot[24];
        #pragma unroll
        for (int k = 0; k < 24; k++)
            tot[k] = sh[0][k] + sh[1][k] + sh[2][k] + sh[3][k];
        const double Ns[3] = {17328.0, 69312.0, 277248.0};
        double loss = 0.0;
        for (int s = 0; s < 3; s++) {
            double N = Ns[s];
            double lx = tot[s * 7 + 0] / N;
            double ly = tot[s * 7 + 1] / N;
            double lw = tot[s * 7 + 2] / N;
            double lh = tot[s * 7 + 3] / N;
            double c1 = tot[s * 7 + 4] / N;
            double np = tot[s * 7 + 6];
            double lcls = (np > 0.0) ? (tot[s * 7 + 5] / (np * 80.0)) : 0.0;
            double c2 = 0.5 * tot[21 + s] / N;
            loss += 2.5 * (lx + ly) + 2.5 * (lw + lh) + (c1 + c2) + lcls;
        }
        out[0] = (float)loss;
    }
}

extern "C" void kernel_launch(void* const* d_in, const int* in_sizes, int n_in,
                              void* d_out, int out_size, void* d_ws, size_t ws_size,
                              hipStream_t stream) {
    const float* p0     = (const float*)d_in[0];
    const float* p1     = (const float*)d_in[1];
    const float* p2     = (const float*)d_in[2];
    const float* labels = (const float*)d_in[3];
    float* out = (float*)d_out;

    // ws layout: doubles first (8B aligned), then ints, then bytes
    char* ws = (char*)d_ws;
    double* part2        = (double*)ws;                               // NCAND*8 doubles (153600 B)
    double* part         = part2 + (size_t)NCAND * 8;                 // NCONFBLK*3 doubles (2880 B)
    int* winner          = (int*)(part + NCONFBLK * 3);               // NTOT ints
    int* lcell           = winner + NTOT;                             // NCAND ints
    unsigned char* noobj = (unsigned char*)(lcell + NCAND);           // NTOT bytes

    init_k<<<(NTOT + 255) / 256, 256, 0, stream>>>(winner, lcell, noobj);
    assign_k<<<B_, 64, 0, stream>>>(labels, winner, noobj, lcell);
    pos_k<<<NCAND / 4, 256, 0, stream>>>(p0, p1, p2, labels, winner, lcell, part2);
    conf_k<<<NCONFBLK, 256, 0, stream>>>(p0, p1, p2, noobj, part);
    final_k<<<1, 256, 0, stream>>>(part2, part, out);
}

// Round 3
// 56.401 us; speedup vs baseline: 3.7646x; 1.2000x over previous
//
#include <hip/hip_runtime.h>
#include <math.h>

#define B_    16
#define T_    50
#define C_    80
#define NTOT  363888          // total cells across scales: 17328 + 69312 + 277248
#define OFF0  0
#define OFF1  17328
#define OFF2  86640
#define NBLK  600             // main_k blocks; 4 candidate waves each -> 2400 candidates
#define NCAND 2400
#define NIGN  7200            // 3 scales * 16 batch * 50 labels * 3 anchors

// per-scale grid widths and anchor sizes in grid units (anchor_px / stride, stride = 608/W, exact)
__device__ __constant__ int   cW[3]     = {19, 38, 76};
__device__ __constant__ int   cOFF[3]   = {OFF0, OFF1, OFF2};
__device__ __constant__ float cAW[3][3] = {{3.625f, 4.875f, 11.65625f},
                                           {1.875f, 3.875f, 3.6875f},
                                           {1.25f,  2.0f,   4.125f}};
__device__ __constant__ float cAH[3][3] = {{2.8125f, 6.1875f, 10.1875f},
                                           {3.8125f, 2.8125f, 7.4375f},
                                           {1.625f,  3.75f,   2.875f}};

// min(softplus(x), 100) == the -clip(log p, -100) BCE terms exactly
__device__ __forceinline__ float SPc(float x) {
    float sp = (x > 0.f) ? (x + log1pf(expf(-x))) : log1pf(expf(x));
    return fminf(sp, 100.f);
}

// 16 blocks x 192 threads: wave s handles scale s, lane t handles label t.
// Dedup of winner cells and ignore cells is block-local (collisions only occur
// within the same (scale,b)). Outputs: wcand[2400] winner cell or -1;
// uig[7200] unique ignored cell or -1. Every slot written -> no init kernel.
__global__ __launch_bounds__(192) void assign_k(const float* __restrict__ labels,
                                                int* __restrict__ wcand,
                                                int* __restrict__ uig) {
    int b = blockIdx.x;
    int s = threadIdx.x >> 6;
    int t = threadIdx.x & 63;
    __shared__ int posi[3][64];   // gj*W+gi or -1
    __shared__ int bsta[3][64];   // best anchor index
    __shared__ int imsk[3][64];   // bitmask of anchors with iou > 0.5

    const float* L = labels + (b * T_ + t) * 5;
    float rs = 0.f;
    if (t < T_) rs = L[0] + L[1] + L[2] + L[3] + L[4];
    unsigned long long vb = __ballot(t < T_ && rs > 0.f);
    int nlabel = __popcll(vb);
    bool valid = (t < T_) && (t < nlabel);

    int W = cW[s], HW = W * W;
    int pos = -1, best = 0, msk = 0;
    if (valid) {
        float gx = (L[1] / 608.f) * W, gy = (L[2] / 608.f) * W;
        float gw = (L[3] / 608.f) * W, gh = (L[4] / 608.f) * W;
        int gi = (int)floorf(gx), gj = (int)floorf(gy);
        float best_iou = -1.f;
        #pragma unroll
        for (int a = 0; a < 3; a++) {
            float aw = cAW[s][a], ah = cAH[s][a];
            float inter = (fminf(gw, aw) + 1.f) * (fminf(gh, ah) + 1.f);
            float iou = inter / ((gw + 1.f) * (gh + 1.f) + (aw + 1.f) * (ah + 1.f) - inter + 1e-16f);
            if (iou > best_iou) { best_iou = iou; best = a; }   // first-max wins ties (argmax)
            if (iou > 0.5f) msk |= (1 << a);
        }
        if (gi >= 0 && gi < W && gj >= 0 && gj < W) pos = gj * W + gi;  // OOB -> drop
    }
    posi[s][t] = pos; bsta[s][t] = best; imsk[s][t] = msk;
    __syncthreads();

    // winner iff no later label (higher t) targets the same (pos,best): JAX scatter last-wins
    bool win = (pos >= 0);
    if (win) {
        for (int u = t + 1; u < T_; u++)
            if (posi[s][u] == pos && bsta[s][u] == best) { win = false; break; }
    }
    if (t < T_)
        wcand[s * (B_ * T_) + b * T_ + t] = win ? (cOFF[s] + (b * 3 + best) * HW + pos) : -1;

    // unique ignore entries: keep the first (lowest t) occurrence of each (pos, anchor)
    #pragma unroll
    for (int a = 0; a < 3; a++) {
        int ic = -1;
        if (pos >= 0 && ((msk >> a) & 1)) {
            bool first = true;
            for (int u = 0; u < t; u++)
                if (posi[s][u] == pos && ((imsk[s][u] >> a) & 1)) { first = false; break; }
            if (first) ic = cOFF[s] + (b * 3 + a) * HW + pos;
        }
        if (t < T_) uig[(s * B_ + b) * 150 + t * 3 + a] = ic;
    }
}

// 600 blocks x 256 threads, fused:
//  (1) pos losses: one wave per candidate (blocks are scale-pure: blk/200 = scale)
//  (2) ignore subtraction: thread gid < 7200 handles one unique ignored cell
//  (3) conf streaming: grid-stride sum of SPc(conf logit) over ALL cells (coalesced)
// Each block writes 10 fixed-order double partials: [0..6] pos terms (block's scale),
// [7..9] conf sums per scale.
__global__ __launch_bounds__(256) void main_k(
    const float* __restrict__ p0, const float* __restrict__ p1, const float* __restrict__ p2,
    const float* __restrict__ labels, const int* __restrict__ wcand,
    const int* __restrict__ uig, double* __restrict__ part) {
    int tid = threadIdx.x, lane = tid & 63, wid = tid >> 6;
    int blk = blockIdx.x;
    double o0 = 0, o1 = 0, o2 = 0, o3 = 0, o4 = 0, o5 = 0, o6 = 0;
    double c0 = 0, c1 = 0, c2 = 0;

    // --- (1) pos path ---
    int wg = blk * 4 + wid;                    // candidate id, wave-uniform
    int cell = wcand[wg];
    if (cell >= 0) {                           // wave-uniform branch
        int s = wg / (B_ * T_);
        int bt = wg - s * (B_ * T_);
        int b = bt / T_, t = bt - b * T_;
        int W = cW[s], HW = W * W;
        const float* p = (s == 0) ? p0 : ((s == 1) ? p1 : p2);
        int local = cell - cOFF[s];
        int posid = local % HW;
        int a = (local / HW) % 3;
        int gi = posid % W, gj = posid / W;
        const float* L = labels + (b * T_ + t) * 5;
        int cls = (int)L[0];
        int base = (b * 255 + a * 85) * HW + posid;
        double clsum = 0.0;
        for (int c = lane; c < C_; c += 64) {
            float xc = p[base + (5 + c) * HW];
            clsum += (double)((c == cls) ? SPc(-xc) : SPc(xc));
        }
        #pragma unroll
        for (int off = 32; off; off >>= 1) clsum += __shfl_down(clsum, off);
        if (lane == 0) {
            float gx = (L[1] / 608.f) * W, gy = (L[2] / 608.f) * W;
            float gw = (L[3] / 608.f) * W, gh = (L[4] / 608.f) * W;
            float tx = gx - gi, ty = gy - gj;
            float tw = logf(gw / cAW[s][a] + 1e-16f);
            float th = logf(gh / cAH[s][a] + 1e-16f);
            float x0 = p[base];
            float x1 = p[base + HW];
            float x2 = p[base + 2 * HW];
            float x3 = p[base + 3 * HW];
            float x4 = p[base + 4 * HW];
            o0 = (double)(tx * SPc(-x0) + (1.f - tx) * SPc(x0));
            o1 = (double)(ty * SPc(-x1) + (1.f - ty) * SPc(x1));
            float dw = x2 - tw, dh = x3 - th;
            o2 = (double)(dw * dw);
            o3 = (double)(dh * dh);
            o4 = (double)SPc(-x4);
            o5 = clsum;
            o6 = 1.0;
        }
    }

    // --- (2) ignore subtraction ---
    int gid = blk * 256 + tid;
    if (gid < NIGN) {
        int ic = uig[gid];
        if (ic >= 0) {
            int si = (ic >= OFF2) ? 2 : ((ic >= OFF1) ? 1 : 0);
            int W = cW[si], HW = W * W;
            int local = ic - cOFF[si];
            int ba = local / HW, posid = local % HW;
            const float* p = (si == 0) ? p0 : ((si == 1) ? p1 : p2);
            float x = p[((ba / 3) * 255 + (ba % 3) * 85 + 4) * HW + posid];
            double v = (double)SPc(x);
            if (si == 0) c0 -= v; else if (si == 1) c1 -= v; else c2 -= v;
        }
    }

    // --- (3) conf streaming over all cells (consecutive idx -> consecutive pos: coalesced) ---
    for (int idx = gid; idx < NTOT; idx += NBLK * 256) {
        int si, off;
        const float* p;
        if (idx < OFF1)      { si = 0; off = OFF0; p = p0; }
        else if (idx < OFF2) { si = 1; off = OFF1; p = p1; }
        else                 { si = 2; off = OFF2; p = p2; }
        int W = cW[si], HW = W * W;
        int local = idx - off;
        int ba = local / HW, posid = local % HW;
        float x = p[((ba / 3) * 255 + (ba % 3) * 85 + 4) * HW + posid];
        double v = (double)SPc(x);
        if (si == 0) c0 += v; else if (si == 1) c1 += v; else c2 += v;
    }

    // --- block reduce 10 doubles, fixed order ---
    #pragma unroll
    for (int off = 32; off; off >>= 1) {
        o0 += __shfl_down(o0, off); o1 += __shfl_down(o1, off);
        o2 += __shfl_down(o2, off); o3 += __shfl_down(o3, off);
        o4 += __shfl_down(o4, off); o5 += __shfl_down(o5, off);
        o6 += __shfl_down(o6, off);
        c0 += __shfl_down(c0, off); c1 += __shfl_down(c1, off);
        c2 += __shfl_down(c2, off);
    }
    __shared__ double sh[4][10];
    if (lane == 0) {
        sh[wid][0] = o0; sh[wid][1] = o1; sh[wid][2] = o2; sh[wid][3] = o3;
        sh[wid][4] = o4; sh[wid][5] = o5; sh[wid][6] = o6;
        sh[wid][7] = c0; sh[wid][8] = c1; sh[wid][9] = c2;
    }
    __syncthreads();
    if (tid == 0) {
        #pragma unroll
        for (int k = 0; k < 10; k++)
            part[blk * 10 + k] = sh[0][k] + sh[1][k] + sh[2][k] + sh[3][k];
    }
}

// deterministic tree-reduce of 600 x 10 partials -> scalar loss
__global__ __launch_bounds__(256) void final_k(const double* __restrict__ part,
                                               float* __restrict__ out) {
    int tid = threadIdx.x;
    double acc[3][7];
    double cacc[3] = {0, 0, 0};
    #pragma unroll
    for (int s = 0; s < 3; s++)
        #pragma unroll
        for (int k = 0; k < 7; k++) acc[s][k] = 0.0;
    for (int blk = tid; blk < NBLK; blk += 256) {
        int s = blk / 200;                     // blocks are scale-pure for pos terms
        const double* src = part + blk * 10;
        #pragma unroll
        for (int k = 0; k < 7; k++) acc[s][k] += src[k];
        cacc[0] += src[7]; cacc[1] += src[8]; cacc[2] += src[9];
    }
    int lane = tid & 63, wid = tid >> 6;
    #pragma unroll
    for (int off = 32; off; off >>= 1) {
        #pragma unroll
        for (int s = 0; s < 3; s++)
            #pragma unroll
            for (int k = 0; k < 7; k++) acc[s][k] += __shfl_down(acc[s][k], off);
        #pragma unroll
        for (int s = 0; s < 3; s++) cacc[s] += __shfl_down(cacc[s], off);
    }
    __shared__ double sh[4][24];
    if (lane == 0) {
        #pragma unroll
        for (int s = 0; s < 3; s++) {
            #pragma unroll
            for (int k = 0; k < 7; k++) sh[wid][s * 7 + k] = acc[s][k];
            sh[wid][21 + s] = cacc[s];
        }
    }
    __syncthreads();
    if (tid == 0) {
        double tot[24];
        #pragma unroll
        for (int k = 0; k < 24; k++)
            tot[k] = sh[0][k] + sh[1][k] + sh[2][k] + sh[3][k];
        const double Ns[3] = {17328.0, 69312.0, 277248.0};
        double loss = 0.0;
        for (int s = 0; s < 3; s++) {
            double N = Ns[s];
            double lx = tot[s * 7 + 0] / N;
            double ly = tot[s * 7 + 1] / N;
            double lw = tot[s * 7 + 2] / N;
            double lh = tot[s * 7 + 3] / N;
            double c1 = tot[s * 7 + 4] / N;
            double np = tot[s * 7 + 6];
            double lcls = (np > 0.0) ? (tot[s * 7 + 5] / (np * 80.0)) : 0.0;
            double c2 = 0.5 * tot[21 + s] / N;
            loss += 2.5 * (lx + ly) + 2.5 * (lw + lh) + (c1 + c2) + lcls;
        }
        out[0] = (float)loss;
    }
}

extern "C" void kernel_launch(void* const* d_in, const int* in_sizes, int n_in,
                              void* d_out, int out_size, void* d_ws, size_t ws_size,
                              hipStream_t stream) {
    const float* p0     = (const float*)d_in[0];
    const float* p1     = (const float*)d_in[1];
    const float* p2     = (const float*)d_in[2];
    const float* labels = (const float*)d_in[3];
    float* out = (float*)d_out;

    // ws layout: doubles first (alignment), then ints. All slots are fully
    // rewritten every call -> no init kernel, no stale-state hazard.
    char* ws = (char*)d_ws;
    double* part = (double*)ws;                     // NBLK*10 doubles (48000 B)
    int* wcand   = (int*)(part + NBLK * 10);        // NCAND ints (9600 B)
    int* uig     = wcand + NCAND;                   // NIGN ints (28800 B)

    assign_k<<<B_, 192, 0, stream>>>(labels, wcand, uig);
    main_k<<<NBLK, 256, 0, stream>>>(p0, p1, p2, labels, wcand, uig, part);
    final_k<<<1, 256, 0, stream>>>(part, out);
}